// Round 3
// baseline (102.175 us; speedup 1.0000x reference)
//
#include <hip/hip_runtime.h>
#include <stdint.h>

#define DIM     128
#define NMEM    16384
#define NQ_TOT  2048
#define TQ      64                    // queries per WG (R11: halved for 3 blocks/CU)
#define TN      64                    // mem rows per iter
#define NTILES_TOT (NMEM / TN)        // 256
#define QROWS   (NQ_TOT / TQ)         // 32
#define SHIFT   30.0f
#define PSTR    72                    // Ps row stride (shorts): 144B, 16B-aligned

typedef short    s8v __attribute__((ext_vector_type(8)));
typedef _Float16 h8v __attribute__((ext_vector_type(8)));
typedef float    f4v __attribute__((ext_vector_type(4)));

// ---- workspace layout (bytes) ----
#define OFF_MF16  0u
#define OFF_MHIT  (4u << 20)
#define OFF_NUM   (8u << 20)
#define NUM_BYTES(c)  ((uint32_t)(c) * NQ_TOT * DIM * 2u)   // bf16 partials
#define OFF_DEN(c)    (OFF_NUM + NUM_BYTES(c))
#define WS_NEED(c)    ((size_t)(OFF_DEN(c) + (uint32_t)(c) * NQ_TOT * 4u))

__device__ __forceinline__ uint16_t f2bf(float x) {
    uint32_t u = __float_as_uint(x);
    uint32_t r = u + 0x7fffu + ((u >> 16) & 1u);   // RNE
    return (uint16_t)(r >> 16);
}
__device__ __forceinline__ float bf2f(uint16_t h) {
    return __uint_as_float(((uint32_t)h) << 16);
}
__device__ __forceinline__ uint16_t f2h(float x) {  // fp16 RNE via v_cvt_f16_f32
    union { _Float16 h; uint16_t u; } c;
    c.h = (_Float16)x;
    return c.u;
}

// ==== pre-pass: fp32 memory -> fp16 M (row-major) + bf16 M^T ====
__global__ __launch_bounds__(256)
void convert_kernel(const float* __restrict__ mem, uint16_t* __restrict__ mf16,
                    uint16_t* __restrict__ mhit) {
    __shared__ uint16_t T[DIM * 65];           // [d][n], stride 65 breaks bank conflict
    const int b  = blockIdx.x;                 // 256 blocks x 64 rows
    const int t  = threadIdx.x;
    const int n0 = b * 64;
    #pragma unroll
    for (int k = 0; k < 8; ++k) {
        const int idx4 = t + k * 256;
        const int r    = idx4 >> 5;
        const int c4   = idx4 & 31;
        const float4 v = ((const float4*)(mem + (size_t)(n0 + r) * DIM))[c4];
        *(ushort4*)&mf16[(size_t)(n0 + r) * DIM + c4 * 4] =
            make_ushort4(f2h(v.x), f2h(v.y), f2h(v.z), f2h(v.w));
        T[(c4 * 4 + 0) * 65 + r] = f2bf(v.x);
        T[(c4 * 4 + 1) * 65 + r] = f2bf(v.y);
        T[(c4 * 4 + 2) * 65 + r] = f2bf(v.z);
        T[(c4 * 4 + 3) * 65 + r] = f2bf(v.w);
    }
    __syncthreads();
    #pragma unroll
    for (int p = 0; p < 4; ++p) {
        const int d    = (t >> 3) + p * 32;
        const int part = t & 7;
        uint16_t tmp[8];
        #pragma unroll
        for (int e = 0; e < 8; ++e) tmp[e] = T[d * 65 + part * 8 + e];
        *(uint4*)&mhit[(size_t)d * NMEM + n0 + part * 8] = *(const uint4*)tmp;
    }
}

// ==== main attention: TQ=64, q-split fp16 QK, bf16 PV ========================
// R11: R10's sealed counted-vmcnt pipeline, re-decomposed for occupancy.
// R9/R10 showed the barrier drains were NOT the bottleneck (deep sync
// restructure = -1.3us) -> attn is latency-bound at 2 blocks/CU. R11 halves
// per-block q-state (TQ 128->64): LDS 51.7KB->42KB, VGPR ~110, so
// __launch_bounds__(256,3) gives 3 blocks/CU (12 waves/CU, +50% TLP).
// Grid 1024 = 32 qrows x 32 chunks; per-wave: 16 queries (1 q-tile).
// Staging/swizzles/numerics identical to R10.
template <int NCHK>
__global__ __launch_bounds__(256, 3)
void attn_kernel(const float* __restrict__ query,
                 const uint16_t* __restrict__ mf16,
                 const uint16_t* __restrict__ mhit,
                 uint16_t* __restrict__ num, float* __restrict__ den) {
    // carve: MsF16 8192 | MsT 8192 | Ps 64*72=4608 -> 20992 shorts (41984 B)
    __shared__ __align__(16) uint16_t SM[20992];
    uint16_t* MsF16 = SM;                      // [n64][d-granule^swz] fp16
    uint16_t* MsT   = SM + 8192;               // [d128][n-granule^swz] bf16
    uint16_t* Ps    = SM + 16384;              // [q64][PSTR] bf16
    float*    Red   = (float*)Ps;              // [64] overlays Ps after the loop

    const int tid   = threadIdx.x;
    const int wv    = tid >> 6;
    const int lane  = tid & 63;
    const int l16   = lane & 15;
    const int quad  = lane >> 4;
    const int bx    = blockIdx.x;
    constexpr int CPX = NCHK / 8;              // chunks pinned per XCD
    const int xcd   = bx & 7;
    const int j     = bx >> 3;
    const int chunk = xcd * CPX + (j % CPX);
    const int qrow  = j / CPX;                 // 0..QROWS-1
    const int q0    = qrow * TQ;
    constexpr int ITERS = NTILES_TOT / NCHK;
    const int nbase = chunk * (NMEM / NCHK);

    // ---- stage tile 0: each wave issues its 4 F then its 4 T loads ----
    #pragma unroll
    for (int ii = 0; ii < 4; ++ii) {
        const int fid = wv * 4 + ii;
        const int s = fid * 64 + lane;
        const int r = s >> 4, c = (s & 15) ^ (r & 7);
        const uint16_t* g = mf16 + (size_t)(nbase + r) * DIM + c * 8;
        __builtin_amdgcn_global_load_lds(
            (const __attribute__((address_space(1))) void*)g,
            (__attribute__((address_space(3))) void*)&MsF16[fid * 512], 16, 0, 0);
    }
    #pragma unroll
    for (int ii = 0; ii < 4; ++ii) {
        const int jj = wv * 4 + ii;
        const int s = jj * 64 + lane;
        const int d = s >> 3, c = (s & 7) ^ (d & 7);
        const uint16_t* g = mhit + (size_t)d * NMEM + nbase + c * 8;
        __builtin_amdgcn_global_load_lds(
            (const __attribute__((address_space(1))) void*)g,
            (__attribute__((address_space(3))) void*)&MsT[jj * 512], 16, 0, 0);
    }

    // ---- Q fragments for this wave's 16-query QK slice (fp16) ----
    h8v qf[4];
    {
        const float* qp = query + (size_t)(q0 + wv * 16 + l16) * DIM + quad * 8;
        #pragma unroll
        for (int ks = 0; ks < 4; ++ks) {
            const float4 a = *(const float4*)(qp + ks * 32);
            const float4 b = *(const float4*)(qp + ks * 32 + 4);
            h8v vh;
            vh[0] = (_Float16)a.x; vh[1] = (_Float16)a.y;
            vh[2] = (_Float16)a.z; vh[3] = (_Float16)a.w;
            vh[4] = (_Float16)b.x; vh[5] = (_Float16)b.y;
            vh[6] = (_Float16)b.z; vh[7] = (_Float16)b.w;
            qf[ks] = vh;
        }
    }

    f4v oacc[4][2];                            // PV acc: 4 q-tiles x 2 d-tiles
    float dacc[4];                             // den partials: 4 rg
    #pragma unroll
    for (int qt = 0; qt < 4; ++qt) {
        oacc[qt][0] = (f4v){0.f, 0.f, 0.f, 0.f};
        oacc[qt][1] = (f4v){0.f, 0.f, 0.f, 0.f};
    }
    #pragma unroll
    for (int i = 0; i < 4; ++i) dacc[i] = 0.f;

    for (int it = 0; it < ITERS; ++it) {
        // next tile base (last iter: clamp to nbase -> harmless in-bounds refetch,
        // landing DMA is drained by the post-loop __syncthreads before SM reuse)
        const int nnx = nbase + ((it + 1 == ITERS) ? 0 : (it + 1) * TN);

        // F[it] landed (own 4 oldest); T[it] (4) stays in flight. lgkmcnt(0)
        // forces this wave's prev-iter PV ds_reads (cross-wave Ps!) to complete
        // BEFORE the rendezvous, so post-barrier Ps writes can't corrupt them.
        asm volatile("s_waitcnt vmcnt(4) lgkmcnt(0)" ::: "memory");
        __builtin_amdgcn_s_barrier();
        __builtin_amdgcn_sched_barrier(0);

        // ---- QK^T (q-split, fp16): wave wv computes S[its 16 q][all 64 n] --
        f4v sacc[4];
        #pragma unroll
        for (int nt = 0; nt < 4; ++nt)
            sacc[nt] = (f4v){0.f, 0.f, 0.f, 0.f};
        #pragma unroll
        for (int nt = 0; nt < 4; ++nt) {
            const int r   = nt * 16 + l16;
            const int rsw = r & 7;
            #pragma unroll
            for (int ks = 0; ks < 4; ++ks) {
                const int c = ks * 4 + quad;
                const h8v bm = *(const h8v*)&MsF16[r * DIM + ((c ^ rsw) << 3)];
                sacc[nt] = __builtin_amdgcn_mfma_f32_16x16x32_f16(qf[ks], bm, sacc[nt], 0, 0, 0);
            }
        }

        // ---- exp + P write (bf16, num/den consistent) ----
        #pragma unroll
        for (int nt = 0; nt < 4; ++nt)
            #pragma unroll
            for (int rg = 0; rg < 4; ++rg) {
                const float p = __expf(sacc[nt][rg] - SHIFT);
                const uint16_t pb = f2bf(p);
                dacc[rg] += bf2f(pb);
                const int qloc = wv * 16 + quad * 4 + rg;
                Ps[qloc * PSTR + nt * 16 + l16] = pb;
            }

        // Ps visible to all waves; also proves all waves' QK reads of MsF16[it]
        // completed -> safe to start overwriting it with F[it+1].
        asm volatile("s_waitcnt lgkmcnt(0)" ::: "memory");
        __builtin_amdgcn_s_barrier();
        __builtin_amdgcn_sched_barrier(0);

        // ---- issue F[it+1] (hides under PV) ----
        #pragma unroll
        for (int ii = 0; ii < 4; ++ii) {
            const int fid = wv * 4 + ii;
            const int s = fid * 64 + lane;
            const int r = s >> 4, c = (s & 15) ^ (r & 7);
            const uint16_t* g = mf16 + (size_t)(nnx + r) * DIM + c * 8;
            __builtin_amdgcn_global_load_lds(
                (const __attribute__((address_space(1))) void*)g,
                (__attribute__((address_space(3))) void*)&MsF16[fid * 512], 16, 0, 0);
        }

        // T[it] landed (own 4 oldest; exactly the d-rows this wave reads below).
        asm volatile("s_waitcnt vmcnt(4)" ::: "memory");

        // ---- PV (d-split): wave wv owns d in [wv*32, wv*32+32) ----
        #pragma unroll
        for (int ksP = 0; ksP < 2; ++ksP) {
            s8v bt[2];
            #pragma unroll
            for (int dt = 0; dt < 2; ++dt) {
                const int d  = wv * 32 + dt * 16 + l16;
                const int cg = ksP * 4 + quad;
                bt[dt] = *(const s8v*)&MsT[d * TN + ((cg ^ (d & 7)) << 3)];
            }
            #pragma unroll
            for (int qt = 0; qt < 4; ++qt) {
                const int q = qt * 16 + l16;
                const s8v pf = *(const s8v*)&Ps[q * PSTR + ksP * 32 + quad * 8];
                oacc[qt][0] = __builtin_amdgcn_mfma_f32_16x16x32_bf16(pf, bt[0], oacc[qt][0], 0, 0, 0);
                oacc[qt][1] = __builtin_amdgcn_mfma_f32_16x16x32_bf16(pf, bt[1], oacc[qt][1], 0, 0, 0);
            }
        }

        // Own PV ds_reads complete before their MsT rows are DMA-overwritten.
        asm volatile("s_waitcnt lgkmcnt(0)" ::: "memory");

        // ---- issue T[it+1]: overwrites only rows this wave already consumed --
        #pragma unroll
        for (int ii = 0; ii < 4; ++ii) {
            const int jj = wv * 4 + ii;
            const int s = jj * 64 + lane;
            const int d = s >> 3, c = (s & 7) ^ (d & 7);
            const uint16_t* g = mhit + (size_t)d * NMEM + nnx + c * 8;
            __builtin_amdgcn_global_load_lds(
                (const __attribute__((address_space(1))) void*)g,
                (__attribute__((address_space(3))) void*)&MsT[jj * 512], 16, 0, 0);
        }
    }

    // ---- denominator: reduce over l16 (each q lives in exactly one wave) ----
    #pragma unroll
    for (int m = 1; m <= 8; m <<= 1)
        #pragma unroll
        for (int i = 0; i < 4; ++i)
            dacc[i] += __shfl_xor(dacc[i], m, 64);
    __syncthreads();                           // full drain (incl. tail DMA); SM reusable
    if (l16 == 0) {
        #pragma unroll
        for (int rg = 0; rg < 4; ++rg)
            Red[wv * 16 + quad * 4 + rg] = dacc[rg];
    }
    // ---- O merge into LDS (bf16) for coalesced stores ----
    uint16_t* Obuf = SM;                       // 64 q x 128 d x 2B = 16 KB (Ms region)
    #pragma unroll
    for (int qt = 0; qt < 4; ++qt)
        #pragma unroll
        for (int dt = 0; dt < 2; ++dt)
            #pragma unroll
            for (int rg = 0; rg < 4; ++rg) {
                const int qq = qt * 16 + quad * 4 + rg;
                const int dd = wv * 32 + dt * 16 + l16;
                Obuf[qq * DIM + dd] = f2bf(oacc[qt][dt][rg]);
            }
    __syncthreads();
    if (tid < TQ) den[chunk * NQ_TOT + q0 + tid] = Red[tid];
    {
        uint4* dst = (uint4*)(num + ((size_t)chunk * NQ_TOT + q0) * DIM);
        const uint4* src = (const uint4*)Obuf;
        #pragma unroll
        for (int k = 0; k < 4; ++k) {
            const int f = tid + k * 256;       // 1024 uint4s (16 KB)
            dst[f] = src[f];
        }
    }
}

// ============ final reduce over chunks + normalize ============
template <int NCHK>
__global__ __launch_bounds__(256)
void reduce_kernel(const uint16_t* __restrict__ num, const float* __restrict__ den,
                   float* __restrict__ out) {
    const int f = blockIdx.x * 256 + threadIdx.x;   // 65536 groups of 4
    const int q = f >> 5;
    float4 ns = make_float4(0.f, 0.f, 0.f, 0.f);
    float ds = 0.f;
    #pragma unroll
    for (int c = 0; c < NCHK; ++c) {
        const ushort4 v = ((const ushort4*)num)[c * (NQ_TOT * DIM / 4) + f];
        ns.x += bf2f(v.x); ns.y += bf2f(v.y); ns.z += bf2f(v.z); ns.w += bf2f(v.w);
        ds += den[c * NQ_TOT + q];
    }
    const float inv = 1.0f / ds;
    ((float4*)out)[f] = make_float4(ns.x * inv, ns.y * inv, ns.z * inv, ns.w * inv);
}

// ============ fallback (round-1 fp32 kernel) if ws too small ============
#define FTQ 8
#define FTN 64
#define FNTILES (NMEM / FTN)
#define FBLOCK 512
#define MPAD 132
#define PPAD 68

__global__ __launch_bounds__(FBLOCK, 2)
void sparse_attn_fp32(const float* __restrict__ query,
                      const float* __restrict__ memory,
                      float* __restrict__ out) {
    __shared__ float Qs[FTQ * MPAD];
    __shared__ float Ms[FTN * MPAD];
    __shared__ float Psh[FTQ * PPAD];
    __shared__ float Rd[FTQ * PPAD];
    const int tid = threadIdx.x;
    const int q = tid & 7, rest = tid >> 3;
    const int ng = rest, dg = rest & 31, half = rest >> 5;
    const long q0 = (long)blockIdx.x * FTQ;
    if (tid < FTQ * DIM / 4) {
        const float4 v = ((const float4*)(query + q0 * DIM))[tid];
        *(float4*)&Qs[(tid >> 5) * MPAD + ((tid & 31) << 2)] = v;
    }
    float4 pf[4];
    {
        const float4* msrc = (const float4*)memory;
        #pragma unroll
        for (int k = 0; k < 4; ++k) pf[k] = msrc[tid + k * FBLOCK];
    }
    float4 acc = make_float4(0.f, 0.f, 0.f, 0.f);
    float l_part = 0.f;
    for (int t = 0; t < FNTILES; ++t) {
        __syncthreads();
        #pragma unroll
        for (int k = 0; k < 4; ++k) {
            const int f4 = tid + k * FBLOCK;
            *(float4*)&Ms[(f4 >> 5) * MPAD + ((f4 & 31) << 2)] = pf[k];
        }
        __syncthreads();
        if (t + 1 < FNTILES) {
            const float4* msrc = (const float4*)(memory + (long)(t + 1) * FTN * DIM);
            #pragma unroll
            for (int k = 0; k < 4; ++k) pf[k] = msrc[tid + k * FBLOCK];
        }
        float4 s4 = make_float4(0.f, 0.f, 0.f, 0.f);
        const float* qrow = &Qs[q * MPAD];
        const float* mrow = &Ms[ng * MPAD];
        #pragma unroll
        for (int jj = 0; jj < 32; ++jj) {
            const float4 qv = *(const float4*)&qrow[jj * 4];
            const float4 mv = *(const float4*)&mrow[jj * 4];
            s4.x += qv.x * mv.x; s4.y += qv.y * mv.y;
            s4.z += qv.z * mv.z; s4.w += qv.w * mv.w;
        }
        const float p = __expf(((s4.x + s4.y) + (s4.z + s4.w)) - SHIFT);
        Psh[q * PPAD + ng] = p;
        l_part += p;
        __syncthreads();
        #pragma unroll
        for (int n = 0; n < 32; ++n) {
            const int nn = half * 32 + n;
            const float pw = Psh[q * PPAD + nn];
            const float4 mv = *(const float4*)&Ms[nn * MPAD + dg * 4];
            acc.x += pw * mv.x; acc.y += pw * mv.y;
            acc.z += pw * mv.z; acc.w += pw * mv.w;
        }
    }
    __syncthreads();
    Rd[q * PPAD + rest] = l_part;
    if (half == 1) *(float4*)&Ms[q * MPAD + dg * 4] = acc;
    __syncthreads();
    if (half == 0) {
        const float4 o2 = *(const float4*)&Ms[q * MPAD + dg * 4];
        float l = 0.f;
        #pragma unroll 8
        for (int i = 0; i < 64; ++i) l += Rd[q * PPAD + i];
        const float inv = 1.0f / l;
        float4 o;
        o.x = (acc.x + o2.x) * inv; o.y = (acc.y + o2.y) * inv;
        o.z = (acc.z + o2.z) * inv; o.w = (acc.w + o2.w) * inv;
        *(float4*)(out + (q0 + q) * DIM + dg * 4) = o;
    }
}

extern "C" void kernel_launch(void* const* d_in, const int* in_sizes, int n_in,
                              void* d_out, int out_size, void* d_ws, size_t ws_size,
                              hipStream_t stream) {
    const float* query  = (const float*)d_in[0];
    const float* memory = (const float*)d_in[1];
    float* out = (float*)d_out;
    if (ws_size >= WS_NEED(16)) {
        uint16_t* mf16 = (uint16_t*)((char*)d_ws + OFF_MF16);
        uint16_t* mhit = (uint16_t*)((char*)d_ws + OFF_MHIT);
        uint16_t* num  = (uint16_t*)((char*)d_ws + OFF_NUM);
        convert_kernel<<<NMEM / 64, 256, 0, stream>>>(memory, mf16, mhit);
        if (ws_size >= WS_NEED(32)) {
            float* den = (float*)((char*)d_ws + OFF_DEN(32));
            attn_kernel<32><<<QROWS * 32, 256, 0, stream>>>(query, mf16, mhit, num, den);
            reduce_kernel<32><<<NQ_TOT * DIM / 4 / 256, 256, 0, stream>>>(num, den, out);
        } else {
            float* den = (float*)((char*)d_ws + OFF_DEN(16));
            attn_kernel<16><<<QROWS * 16, 256, 0, stream>>>(query, mf16, mhit, num, den);
            reduce_kernel<16><<<NQ_TOT * DIM / 4 / 256, 256, 0, stream>>>(num, den, out);
        }
    } else {
        sparse_attn_fp32<<<NQ_TOT / FTQ, FBLOCK, 0, stream>>>(query, memory, out);
    }
}

// Round 7
// 97.723 us; speedup vs baseline: 1.0456x; 1.0456x over previous
//
#include <hip/hip_runtime.h>
#include <stdint.h>

#define DIM     128
#define NMEM    16384
#define NQ_TOT  2048
#define TQ      128                   // queries per WG (q-split QK across waves)
#define TN      64                    // mem rows per iter
#define NTILES_TOT (NMEM / TN)        // 256
#define QROWS   (NQ_TOT / TQ)         // 16
#define SHIFT   30.0f
#define PSTR    88                    // Ps^T row stride (shorts): 176B ≡ 0 mod 16

typedef short    s8v __attribute__((ext_vector_type(8)));
typedef _Float16 h8v __attribute__((ext_vector_type(8)));
typedef float    f4v __attribute__((ext_vector_type(4)));

// ---- workspace layout (bytes) ----
#define OFF_MF16  0u
#define OFF_MHIT  (4u << 20)
#define OFF_NUM   (8u << 20)
#define NUM_BYTES(c)  ((uint32_t)(c) * NQ_TOT * DIM * 2u)   // bf16 partials
#define OFF_DEN(c)    (OFF_NUM + NUM_BYTES(c))
#define WS_NEED(c)    ((size_t)(OFF_DEN(c) + (uint32_t)(c) * NQ_TOT * 4u))

__device__ __forceinline__ uint16_t f2bf(float x) {
    uint32_t u = __float_as_uint(x);
    uint32_t r = u + 0x7fffu + ((u >> 16) & 1u);   // RNE
    return (uint16_t)(r >> 16);
}
__device__ __forceinline__ float bf2f(uint16_t h) {
    return __uint_as_float(((uint32_t)h) << 16);
}
__device__ __forceinline__ uint16_t f2h(float x) {  // fp16 RNE via v_cvt_f16_f32
    union { _Float16 h; uint16_t u; } c;
    c.h = (_Float16)x;
    return c.u;
}

// ==== pre-pass: fp32 memory -> fp16 M (row-major) + bf16 M^T ====
__global__ __launch_bounds__(256)
void convert_kernel(const float* __restrict__ mem, uint16_t* __restrict__ mf16,
                    uint16_t* __restrict__ mhit) {
    __shared__ uint16_t T[DIM * 65];           // [d][n], stride 65 breaks bank conflict
    const int b  = blockIdx.x;                 // 256 blocks x 64 rows
    const int t  = threadIdx.x;
    const int n0 = b * 64;
    #pragma unroll
    for (int k = 0; k < 8; ++k) {
        const int idx4 = t + k * 256;
        const int r    = idx4 >> 5;
        const int c4   = idx4 & 31;
        const float4 v = ((const float4*)(mem + (size_t)(n0 + r) * DIM))[c4];
        *(ushort4*)&mf16[(size_t)(n0 + r) * DIM + c4 * 4] =
            make_ushort4(f2h(v.x), f2h(v.y), f2h(v.z), f2h(v.w));
        T[(c4 * 4 + 0) * 65 + r] = f2bf(v.x);
        T[(c4 * 4 + 1) * 65 + r] = f2bf(v.y);
        T[(c4 * 4 + 2) * 65 + r] = f2bf(v.z);
        T[(c4 * 4 + 3) * 65 + r] = f2bf(v.w);
    }
    __syncthreads();
    #pragma unroll
    for (int p = 0; p < 4; ++p) {
        const int d    = (t >> 3) + p * 32;
        const int part = t & 7;
        uint16_t tmp[8];
        #pragma unroll
        for (int e = 0; e < 8; ++e) tmp[e] = T[d * 65 + part * 8 + e];
        *(uint4*)&mhit[(size_t)d * NMEM + n0 + part * 8] = *(const uint4*)tmp;
    }
}

// ==== main attention: TQ=128, swapped QK, Ps^T via LDS (vectorized) =========
// R15: R10's proven skeleton; ONLY the QK orientation + Ps layout change.
//  - QK computes mfma(M,Q) -> S^T: sacc[qt][nt][rg] at lane (l16,quad) =
//    S[n = nt*16 + 4*quad + rg][q = q0 + wv*32 + qt*16 + l16].
//    (operand swap is exact: original kernel proves both operands use the
//    same lane->k map, so mfma(B-data,A-data) = (A.B)^T; D-layout m89-proven)
//  - exp + f2bf (proven helper, no cvt_pk) packs 4 consecutive-n values into
//    one uint2 -> ONE ds_write_b64 per (qt,nt): 8 b64 writes/lane vs R10's
//    32 scalar b16 (4x fewer LDS write ops). Ps^T rows are [q][n] contiguous.
//  - PV is R10 VERBATIM (pf = Ps[q*PSTR + ksP*32 + quad*8] b128, bt from MsT,
//    same oacc layout, same epilogue). PSTR 72->88: 176B stride stays
//    16B-aligned and cuts the pf-read conflict class ~8-way -> ~2-way.
//  - den: per-lane (q=l16) sums 16 n per qt; shfl over quads; direct global
//    write from quad==0 lanes. Red LDS buffer deleted.
// Sync skeleton, staging ownership (wave wv stages+reads MsT d-rows
// [wv*32,wv*32+32)), vmcnt(4)/lgkmcnt discipline: R10 verbatim.
template <int NCHK>
__global__ __launch_bounds__(256, 2)
void attn_kernel(const float* __restrict__ query,
                 const uint16_t* __restrict__ mf16,
                 const uint16_t* __restrict__ mhit,
                 uint16_t* __restrict__ num, float* __restrict__ den) {
    // carve: MsF16 8192 | MsT 8192 | Ps^T 128*88=11264 -> 27648 shorts (55296B)
    __shared__ __align__(16) uint16_t SM[27648];
    uint16_t* MsF16 = SM;                      // [n64][d-granule^swz] fp16
    uint16_t* MsT   = SM + 8192;               // [d128][n-granule^swz] bf16
    uint16_t* Ps    = SM + 16384;              // [q128][PSTR] bf16 (P^T: [q][n])

    const int tid   = threadIdx.x;
    const int wv    = tid >> 6;
    const int lane  = tid & 63;
    const int l16   = lane & 15;
    const int quad  = lane >> 4;
    const int bx    = blockIdx.x;
    constexpr int CPX = NCHK / 8;              // chunks pinned per XCD
    const int xcd   = bx & 7;
    const int j     = bx >> 3;
    const int chunk = xcd * CPX + (j % CPX);
    const int qrow  = j / CPX;                 // 0..QROWS-1
    const int q0    = qrow * TQ;
    constexpr int ITERS = NTILES_TOT / NCHK;
    const int nbase = chunk * (NMEM / NCHK);

    // ---- stage tile 0: each wave issues its 4 F then its 4 T loads ----
    #pragma unroll
    for (int ii = 0; ii < 4; ++ii) {
        const int fid = wv * 4 + ii;
        const int s = fid * 64 + lane;
        const int r = s >> 4, c = (s & 15) ^ (r & 7);
        const uint16_t* g = mf16 + (size_t)(nbase + r) * DIM + c * 8;
        __builtin_amdgcn_global_load_lds(
            (const __attribute__((address_space(1))) void*)g,
            (__attribute__((address_space(3))) void*)&MsF16[fid * 512], 16, 0, 0);
    }
    #pragma unroll
    for (int ii = 0; ii < 4; ++ii) {
        const int jj = wv * 4 + ii;
        const int s = jj * 64 + lane;
        const int d = s >> 3, c = (s & 7) ^ (d & 7);
        const uint16_t* g = mhit + (size_t)d * NMEM + nbase + c * 8;
        __builtin_amdgcn_global_load_lds(
            (const __attribute__((address_space(1))) void*)g,
            (__attribute__((address_space(3))) void*)&MsT[jj * 512], 16, 0, 0);
    }

    // ---- Q fragments for this wave's 32-query slice (fp16), q on l16 ----
    h8v qf[2][4];
    #pragma unroll
    for (int qt = 0; qt < 2; ++qt) {
        const float* qp = query + (size_t)(q0 + wv * 32 + qt * 16 + l16) * DIM + quad * 8;
        #pragma unroll
        for (int ks = 0; ks < 4; ++ks) {
            const float4 a = *(const float4*)(qp + ks * 32);
            const float4 b = *(const float4*)(qp + ks * 32 + 4);
            h8v vh;
            vh[0] = (_Float16)a.x; vh[1] = (_Float16)a.y;
            vh[2] = (_Float16)a.z; vh[3] = (_Float16)a.w;
            vh[4] = (_Float16)b.x; vh[5] = (_Float16)b.y;
            vh[6] = (_Float16)b.z; vh[7] = (_Float16)b.w;
            qf[qt][ks] = vh;
        }
    }

    f4v oacc[8][2];                            // PV acc: 8 q-tiles x 2 d-tiles (R10)
    float dacc[2] = {0.f, 0.f};                // den partials: per qt, q = l16
    #pragma unroll
    for (int qt = 0; qt < 8; ++qt) {
        oacc[qt][0] = (f4v){0.f, 0.f, 0.f, 0.f};
        oacc[qt][1] = (f4v){0.f, 0.f, 0.f, 0.f};
    }

    for (int it = 0; it < ITERS; ++it) {
        // next tile base (last iter: clamp -> harmless in-bounds refetch,
        // drained by the post-loop __syncthreads before SM reuse)
        const int nnx = nbase + ((it + 1 == ITERS) ? 0 : (it + 1) * TN);

        // F[it] landed (own 4 oldest); T[it] (4) stays in flight. lgkmcnt(0)
        // drains this wave's prev-iter PV ds_reads (cross-wave Ps!) before the
        // rendezvous, so post-barrier Ps writes can't corrupt them.
        asm volatile("s_waitcnt vmcnt(4) lgkmcnt(0)" ::: "memory");
        __builtin_amdgcn_s_barrier();
        __builtin_amdgcn_sched_barrier(0);

        // ---- QK^T swapped: sacc = mfma(Mrow-frag, Q-frag) = S^T ----
        f4v sacc[2][4];
        #pragma unroll
        for (int qt = 0; qt < 2; ++qt)
            #pragma unroll
            for (int nt = 0; nt < 4; ++nt)
                sacc[qt][nt] = (f4v){0.f, 0.f, 0.f, 0.f};
        #pragma unroll
        for (int nt = 0; nt < 4; ++nt) {
            const int r   = nt * 16 + l16;     // A-row = mem row (lane l16)
            const int rsw = r & 7;
            #pragma unroll
            for (int ks = 0; ks < 4; ++ks) {
                const int c = ks * 4 + quad;
                const h8v bm = *(const h8v*)&MsF16[r * DIM + ((c ^ rsw) << 3)];
                #pragma unroll
                for (int qt = 0; qt < 2; ++qt)
                    sacc[qt][nt] = __builtin_amdgcn_mfma_f32_16x16x32_f16(bm, qf[qt][ks], sacc[qt][nt], 0, 0, 0);
            }
        }

        // ---- exp + P^T write: 4 consecutive n per lane -> one b64 ----
        #pragma unroll
        for (int qt = 0; qt < 2; ++qt) {
            const int qloc = wv * 32 + qt * 16 + l16;
            #pragma unroll
            for (int nt = 0; nt < 4; ++nt) {
                const uint16_t pb0 = f2bf(__expf(sacc[qt][nt][0] - SHIFT));
                const uint16_t pb1 = f2bf(__expf(sacc[qt][nt][1] - SHIFT));
                const uint16_t pb2 = f2bf(__expf(sacc[qt][nt][2] - SHIFT));
                const uint16_t pb3 = f2bf(__expf(sacc[qt][nt][3] - SHIFT));
                dacc[qt] += (bf2f(pb0) + bf2f(pb1)) + (bf2f(pb2) + bf2f(pb3));
                uint2 w;
                w.x = (uint32_t)pb0 | ((uint32_t)pb1 << 16);
                w.y = (uint32_t)pb2 | ((uint32_t)pb3 << 16);
                // Ps[q][n = nt*16 + quad*4 + {0..3}] = P[n][q]
                *(uint2*)&Ps[qloc * PSTR + nt * 16 + quad * 4] = w;
            }
        }

        // Ps^T visible to all waves; all QK reads of MsF16[it] completed ->
        // safe to overwrite with F[it+1].
        asm volatile("s_waitcnt lgkmcnt(0)" ::: "memory");
        __builtin_amdgcn_s_barrier();
        __builtin_amdgcn_sched_barrier(0);

        // ---- issue F[it+1] (hides under PV) ----
        #pragma unroll
        for (int ii = 0; ii < 4; ++ii) {
            const int fid = wv * 4 + ii;
            const int s = fid * 64 + lane;
            const int r = s >> 4, c = (s & 15) ^ (r & 7);
            const uint16_t* g = mf16 + (size_t)(nnx + r) * DIM + c * 8;
            __builtin_amdgcn_global_load_lds(
                (const __attribute__((address_space(1))) void*)g,
                (__attribute__((address_space(3))) void*)&MsF16[fid * 512], 16, 0, 0);
        }

        // T[it] landed (own 4 oldest; exactly the d-rows this wave reads below).
        asm volatile("s_waitcnt vmcnt(4)" ::: "memory");

        // ---- PV (R10 verbatim): wave wv owns d in [wv*32, wv*32+32) ----
        #pragma unroll
        for (int ksP = 0; ksP < 2; ++ksP) {
            s8v bt[2];
            #pragma unroll
            for (int dt = 0; dt < 2; ++dt) {
                const int d  = wv * 32 + dt * 16 + l16;
                const int cg = ksP * 4 + quad;
                bt[dt] = *(const s8v*)&MsT[d * TN + ((cg ^ (d & 7)) << 3)];
            }
            #pragma unroll
            for (int qt = 0; qt < 8; ++qt) {
                const int q = qt * 16 + l16;
                const s8v pf = *(const s8v*)&Ps[q * PSTR + ksP * 32 + quad * 8];
                oacc[qt][0] = __builtin_amdgcn_mfma_f32_16x16x32_bf16(pf, bt[0], oacc[qt][0], 0, 0, 0);
                oacc[qt][1] = __builtin_amdgcn_mfma_f32_16x16x32_bf16(pf, bt[1], oacc[qt][1], 0, 0, 0);
            }
        }

        // Own PV ds_reads complete before their MsT rows are DMA-overwritten.
        asm volatile("s_waitcnt lgkmcnt(0)" ::: "memory");

        // ---- issue T[it+1]: overwrites only rows this wave already consumed --
        #pragma unroll
        for (int ii = 0; ii < 4; ++ii) {
            const int jj = wv * 4 + ii;
            const int s = jj * 64 + lane;
            const int d = s >> 3, c = (s & 7) ^ (d & 7);
            const uint16_t* g = mhit + (size_t)d * NMEM + nnx + c * 8;
            __builtin_amdgcn_global_load_lds(
                (const __attribute__((address_space(1))) void*)g,
                (__attribute__((address_space(3))) void*)&MsT[jj * 512], 16, 0, 0);
        }
    }

    // ---- denominator: q = l16; sum the 4 quads' disjoint n-sets ----
    #pragma unroll
    for (int qt = 0; qt < 2; ++qt) {
        dacc[qt] += __shfl_xor(dacc[qt], 16, 64);
        dacc[qt] += __shfl_xor(dacc[qt], 32, 64);
    }
    __syncthreads();                           // full drain (incl. tail DMA); SM reusable
    if (quad == 0) {
        #pragma unroll
        for (int qt = 0; qt < 2; ++qt)
            den[chunk * NQ_TOT + q0 + wv * 32 + qt * 16 + l16] = dacc[qt];
    }
    // ---- O merge into LDS (bf16) for coalesced stores (R10 verbatim) ----
    uint16_t* Obuf = SM;                       // 128 q x 128 d x 2B = 32 KB
    #pragma unroll
    for (int qt = 0; qt < 8; ++qt)
        #pragma unroll
        for (int dt = 0; dt < 2; ++dt)
            #pragma unroll
            for (int rg = 0; rg < 4; ++rg) {
                const int qq = qt * 16 + quad * 4 + rg;
                const int dd = wv * 32 + dt * 16 + l16;
                Obuf[qq * DIM + dd] = f2bf(oacc[qt][dt][rg]);
            }
    __syncthreads();
    {
        uint4* dst = (uint4*)(num + ((size_t)chunk * NQ_TOT + q0) * DIM);
        const uint4* src = (const uint4*)Obuf;
        #pragma unroll
        for (int k = 0; k < 8; ++k) {
            const int f = tid + k * 256;       // 2048 uint4s (32 KB)
            dst[f] = src[f];
        }
    }
}

// ============ final reduce over chunks + normalize ============
template <int NCHK>
__global__ __launch_bounds__(256)
void reduce_kernel(const uint16_t* __restrict__ num, const float* __restrict__ den,
                   float* __restrict__ out) {
    const int f = blockIdx.x * 256 + threadIdx.x;   // 65536 groups of 4
    const int q = f >> 5;
    float4 ns = make_float4(0.f, 0.f, 0.f, 0.f);
    float ds = 0.f;
    #pragma unroll
    for (int c = 0; c < NCHK; ++c) {
        const ushort4 v = ((const ushort4*)num)[c * (NQ_TOT * DIM / 4) + f];
        ns.x += bf2f(v.x); ns.y += bf2f(v.y); ns.z += bf2f(v.z); ns.w += bf2f(v.w);
        ds += den[c * NQ_TOT + q];
    }
    const float inv = 1.0f / ds;
    ((float4*)out)[f] = make_float4(ns.x * inv, ns.y * inv, ns.z * inv, ns.w * inv);
}

// ============ fallback (round-1 fp32 kernel) if ws too small ============
#define FTQ 8
#define FTN 64
#define FNTILES (NMEM / FTN)
#define FBLOCK 512
#define MPAD 132
#define PPAD 68

__global__ __launch_bounds__(FBLOCK, 2)
void sparse_attn_fp32(const float* __restrict__ query,
                      const float* __restrict__ memory,
                      float* __restrict__ out) {
    __shared__ float Qs[FTQ * MPAD];
    __shared__ float Ms[FTN * MPAD];
    __shared__ float Psh[FTQ * PPAD];
    __shared__ float Rd[FTQ * PPAD];
    const int tid = threadIdx.x;
    const int q = tid & 7, rest = tid >> 3;
    const int ng = rest, dg = rest & 31, half = rest >> 5;
    const long q0 = (long)blockIdx.x * FTQ;
    if (tid < FTQ * DIM / 4) {
        const float4 v = ((const float4*)(query + q0 * DIM))[tid];
        *(float4*)&Qs[(tid >> 5) * MPAD + ((tid & 31) << 2)] = v;
    }
    float4 pf[4];
    {
        const float4* msrc = (const float4*)memory;
        #pragma unroll
        for (int k = 0; k < 4; ++k) pf[k] = msrc[tid + k * FBLOCK];
    }
    float4 acc = make_float4(0.f, 0.f, 0.f, 0.f);
    float l_part = 0.f;
    for (int t = 0; t < FNTILES; ++t) {
        __syncthreads();
        #pragma unroll
        for (int k = 0; k < 4; ++k) {
            const int f4 = tid + k * FBLOCK;
            *(float4*)&Ms[(f4 >> 5) * MPAD + ((f4 & 31) << 2)] = pf[k];
        }
        __syncthreads();
        if (t + 1 < FNTILES) {
            const float4* msrc = (const float4*)(memory + (long)(t + 1) * FTN * DIM);
            #pragma unroll
            for (int k = 0; k < 4; ++k) pf[k] = msrc[tid + k * FBLOCK];
        }
        float4 s4 = make_float4(0.f, 0.f, 0.f, 0.f);
        const float* qrow = &Qs[q * MPAD];
        const float* mrow = &Ms[ng * MPAD];
        #pragma unroll
        for (int jj = 0; jj < 32; ++jj) {
            const float4 qv = *(const float4*)&qrow[jj * 4];
            const float4 mv = *(const float4*)&mrow[jj * 4];
            s4.x += qv.x * mv.x; s4.y += qv.y * mv.y;
            s4.z += qv.z * mv.z; s4.w += qv.w * mv.w;
        }
        const float p = __expf(((s4.x + s4.y) + (s4.z + s4.w)) - SHIFT);
        Psh[q * PPAD + ng] = p;
        l_part += p;
        __syncthreads();
        #pragma unroll
        for (int n = 0; n < 32; ++n) {
            const int nn = half * 32 + n;
            const float pw = Psh[q * PPAD + nn];
            const float4 mv = *(const float4*)&Ms[nn * MPAD + dg * 4];
            acc.x += pw * mv.x; acc.y += pw * mv.y;
            acc.z += pw * mv.z; acc.w += pw * mv.w;
        }
    }
    __syncthreads();
    Rd[q * PPAD + rest] = l_part;
    if (half == 1) *(float4*)&Ms[q * MPAD + dg * 4] = acc;
    __syncthreads();
    if (half == 0) {
        const float4 o2 = *(const float4*)&Ms[q * MPAD + dg * 4];
        float l = 0.f;
        #pragma unroll 8
        for (int i = 0; i < 64; ++i) l += Rd[q * PPAD + i];
        const float inv = 1.0f / l;
        float4 o;
        o.x = (acc.x + o2.x) * inv; o.y = (acc.y + o2.y) * inv;
        o.z = (acc.z + o2.z) * inv; o.w = (acc.w + o2.w) * inv;
        *(float4*)(out + (q0 + q) * DIM + dg * 4) = o;
    }
}

extern "C" void kernel_launch(void* const* d_in, const int* in_sizes, int n_in,
                              void* d_out, int out_size, void* d_ws, size_t ws_size,
                              hipStream_t stream) {
    const float* query  = (const float*)d_in[0];
    const float* memory = (const float*)d_in[1];
    float* out = (float*)d_out;
    if (ws_size >= WS_NEED(16)) {
        uint16_t* mf16 = (uint16_t*)((char*)d_ws + OFF_MF16);
        uint16_t* mhit = (uint16_t*)((char*)d_ws + OFF_MHIT);
        uint16_t* num  = (uint16_t*)((char*)d_ws + OFF_NUM);
        convert_kernel<<<NMEM / 64, 256, 0, stream>>>(memory, mf16, mhit);
        if (ws_size >= WS_NEED(32)) {
            float* den = (float*)((char*)d_ws + OFF_DEN(32));
            attn_kernel<32><<<QROWS * 32, 256, 0, stream>>>(query, mf16, mhit, num, den);
            reduce_kernel<32><<<NQ_TOT * DIM / 4 / 256, 256, 0, stream>>>(num, den, out);
        } else {
            float* den = (float*)((char*)d_ws + OFF_DEN(16));
            attn_kernel<16><<<QROWS * 16, 256, 0, stream>>>(query, mf16, mhit, num, den);
            reduce_kernel<16><<<NQ_TOT * DIM / 4 / 256, 256, 0, stream>>>(num, den, out);
        }
    } else {
        sparse_attn_fp32<<<NQ_TOT / FTQ, FBLOCK, 0, stream>>>(query, memory, out);
    }
}